// Round 5
// baseline (247.789 us; speedup 1.0000x reference)
//
#include <hip/hip_runtime.h>
#include <stdint.h>

#define TW_LO 2.10f      // window for the K-th order statistic: 2.326 +/- 6 sigma
#define TW_HI 2.55f
#define LCAP 256         // window-member list cap (E=125, sigma=11 -> +11.8 sigma)
#define DELTA_W 0.2f
#define NITER 5          // float4 loads per ping-pong batch

// Monotone map float -> uint32 (order-preserving) — exact fallback only
static __device__ __forceinline__ unsigned f2u(float x) {
    unsigned b = __float_as_uint(x);
    return (b & 0x80000000u) ? ~b : (b | 0x80000000u);
}
static __device__ __forceinline__ float u2f(unsigned u) {
    unsigned b = (u & 0x80000000u) ? (u & 0x7fffffffu) : ~u;
    return __uint_as_float(b);
}
// Each wave touches only its own LDS slice -> a DS-queue drain suffices;
// no s_barrier anywhere in this kernel.
static __device__ __forceinline__ void wave_lds_fence() {
    asm volatile("s_waitcnt lgkmcnt(0)" ::: "memory");
}

__global__ __launch_bounds__(256) void dtl_rows(const float* __restrict__ in,
                                                const int* __restrict__ targets,
                                                float* __restrict__ ws,
                                                int M, int N, int K) {
    __shared__ float wlist[4][LCAP];
    __shared__ int wcnt[4];

    const int wid = threadIdx.x >> 6;
    const int lane = threadIdx.x & 63;
    const int row = blockIdx.x * 4 + wid;
    if (row >= M) return;          // wave-uniform

    float* __restrict__ mylist = wlist[wid];

    const size_t rowoff = (size_t)row * (size_t)N;
    const float* __restrict__ p = in + rowoff;
    const int tgt = targets[row];

    float posv0 = 0.f;
    if (lane == 0) posv0 = p[tgt];          // issued early
    if (lane == 0) wcnt[wid] = 0;
    wave_lds_fence();

    int chi = 0;                             // per-lane: #{x > TW_HI}
    float sum_hi = 0.f;                      // per-lane: sum (1+x)^2 over x > TW_HI

    auto proc = [&](float x) {
        bool hi = x > TW_HI;                 // certain top-K member
        float t = 1.f + x;
        float z = hi ? t : 0.f;              // branchless accumulate
        sum_hi = fmaf(z, z, sum_hi);
        chi += hi ? 1 : 0;
        if (x > TW_LO && !hi) {              // rare (1.25%): window member
            int idx = atomicAdd(&wcnt[wid], 1);
            if (idx < LCAP) mylist[idx] = x;
        }
    };

    // ---- single pass over the row ----
    int a0 = (int)((4 - (rowoff & 3)) & 3);  // odd row stride: alignment fix
    if (a0 > N) a0 = N;
    const int nv = (N - a0) >> 2;
    const int tail0 = a0 + nv * 4;

    if (lane < a0) proc(p[lane]);
    {
        int c = tail0 + lane;
        if (c < N) proc(p[c]);
    }

    const float4* __restrict__ pv = (const float4*)(p + a0);
    const int perLane = (nv + 63) >> 6;
    const int nBatch = (perLane + NITER - 1) / NITER;
    float4 bufA[NITER], bufB[NITER];
    auto loadBatch = [&](int b, float4* buf) {
#pragma unroll
        for (int it = 0; it < NITER; ++it) {
            int i = (b * NITER + it) * 64 + lane;
            buf[it] = (i < nv) ? pv[i]
                               : make_float4(-1e30f, -1e30f, -1e30f, -1e30f);
        }
    };
    auto procBatch = [&](float4* buf) {
#pragma unroll
        for (int it = 0; it < NITER; ++it) {
            proc(buf[it].x); proc(buf[it].y); proc(buf[it].z); proc(buf[it].w);
        }
    };
    if (nBatch > 0) loadBatch(0, bufA);
    for (int b = 0; b < nBatch; ++b) {       // ping-pong pipeline
        float4* cur = (b & 1) ? bufB : bufA;
        float4* nxt = (b & 1) ? bufA : bufB;
        if (b + 1 < nBatch) loadBatch(b + 1, nxt);
        procBatch(cur);
    }
    wave_lds_fence();

    // ---- wave-reduce chi / sum_hi (all lanes get results) ----
#pragma unroll
    for (int off = 32; off > 0; off >>= 1) {
        chi += __shfl_xor(chi, off);
        sum_hi += __shfl_xor(sum_hi, off);
    }
    const int nW = wcnt[wid];
    const float posv = __shfl(posv0, 0);

    const int j1 = K - chi;                  // rank of K-th largest within window
    const int j2 = K + 1 - chi;              // rank of (K+1)-th largest
    bool done = false;

    if (nW <= LCAP && j1 >= 1 && j2 <= nW) {
        // list -> registers (4/lane); pad 0 (all real members > 2.1 > 0)
        unsigned rl[4];
#pragma unroll
        for (int k2 = 0; k2 < 4; ++k2) {
            int i = lane + 64 * k2;
            rl[k2] = (i < nW) ? __float_as_uint(mylist[i]) : 0u;
        }
        // dual bit-search for j1-th and j2-th largest (positive floats:
        // raw-bit order == value order). Counts packed into one reduction.
        unsigned th1 = 0, th2 = 0;
        for (int bit = 30; bit >= 0; --bit) {
            unsigned tr1 = th1 | (1u << bit), tr2 = th2 | (1u << bit);
            int c1 = 0, c2 = 0;
#pragma unroll
            for (int k2 = 0; k2 < 4; ++k2) {
                c1 += (rl[k2] >= tr1);
                c2 += (rl[k2] >= tr2);
            }
            int pk = c1 | (c2 << 16);        // each total <= 256, no overflow
#pragma unroll
            for (int off = 32; off > 0; off >>= 1) pk += __shfl_xor(pk, off);
            if ((pk & 0xffff) >= j1) th1 = tr1;
            if ((pk >> 16) >= j2) th2 = tr2;
        }
        const float t1v = __uint_as_float(th1);
        const float t2v = __uint_as_float(th2);

        // stats vs t1 / t2 from registers
        int gw1 = 0, gw2 = 0, ct1 = 0;
        float sw1 = 0.f, sw2 = 0.f;
#pragma unroll
        for (int k2 = 0; k2 < 4; ++k2) {
            unsigned u = rl[k2];
            float x = __uint_as_float(u);
            float e = 1.f + x;
            if (u > th1) { gw1++; sw1 = fmaf(e, e, sw1); }
            if (u > th2) { gw2++; sw2 = fmaf(e, e, sw2); }
            ct1 += (u == th1);
        }
        int pk = gw1 | (gw2 << 10) | (ct1 << 20);  // field totals < 1024
#pragma unroll
        for (int off = 32; off > 0; off >>= 1) {
            pk += __shfl_xor(pk, off);
            sw1 += __shfl_xor(sw1, off);
            sw2 += __shfl_xor(sw2, off);
        }
        gw1 = pk & 1023; gw2 = (pk >> 10) & 1023; ct1 = pk >> 20;

        const int g1 = chi + gw1;            // #{S > t1}
        const float S1 = sum_hi + sw1;
        float ans = 0.f;
        bool ok = true;
        if (posv < t1v) {                    // target below K-th: top-K unchanged
            float e = 1.f + t1v;
            ans = S1 + (float)(K - g1) * e * e;
        } else if (posv > t1v) {             // target inside top-K: use top-(K+1)
            const int g2 = chi + gw2;
            const float S2 = sum_hi + sw2;
            float e = 1.f + t2v, pe = 1.f + posv;
            ans = S2 + (float)(K + 1 - g2) * e * e - pe * pe;
        } else {                             // tie with K-th value
            if (g1 + ct1 >= K + 1) {
                float e = 1.f + t1v;
                ans = S1 + (float)(K - g1) * e * e;
            } else ok = false;               // not enough tie copies: fallback
        }
        if (ok) {
            if (lane == 0) {
                float d = 1.f - posv;
                ws[row] = d * d + DELTA_W * ans / (float)K;
            }
            done = true;
        }
    }

    if (!done) {
        // ---- exact global fallback (excludes target by index) ----
        unsigned thr = 0;
        for (int bit = 31; bit >= 0; --bit) {
            unsigned trial = thr | (1u << bit);
            int cnt = 0;
            for (int i = lane; i < N; i += 64) {
                if (i == tgt) continue;
                cnt += (f2u(p[i]) >= trial);
            }
            for (int off = 32; off > 0; off >>= 1) cnt += __shfl_down(cnt, off);
            cnt = __shfl(cnt, 0);
            if (cnt >= K) thr = trial;
        }
        int gt = 0; float s = 0.f;
        for (int i = lane; i < N; i += 64) {
            if (i == tgt) continue;
            unsigned u = f2u(p[i]);
            if (u > thr) { gt++; float e = 1.f + u2f(u); s += e * e; }
        }
        for (int off = 32; off > 0; off >>= 1) {
            gt += __shfl_down(gt, off); s += __shfl_down(s, off);
        }
        if (lane == 0) {
            float et = 1.f + u2f(thr);
            float sum = s + (float)(K - gt) * et * et;
            float d = 1.f - posv;
            ws[row] = d * d + DELTA_W * sum / (float)K;
        }
    }
}

__global__ __launch_bounds__(256) void dtl_reduce(const float* __restrict__ ws,
                                                  float* __restrict__ out, int M) {
    __shared__ float sh[4];
    float s = 0.f;
    for (int i = threadIdx.x; i < M; i += 256) s += ws[i];
    for (int off = 32; off > 0; off >>= 1) s += __shfl_down(s, off);
    int wid = threadIdx.x >> 6;
    if ((threadIdx.x & 63) == 0) sh[wid] = s;
    __syncthreads();
    if (threadIdx.x == 0) out[0] = (sh[0] + sh[1] + sh[2] + sh[3]) / (float)M;
}

extern "C" void kernel_launch(void* const* d_in, const int* in_sizes, int n_in,
                              void* d_out, int out_size, void* d_ws, size_t ws_size,
                              hipStream_t stream) {
    const float* in = (const float*)d_in[0];
    const int* tgt = (const int*)d_in[1];
    const int M = in_sizes[1];
    const int N = in_sizes[0] / M;
    int K = (int)(0.01 * (double)(N - 1));  // matches Python int(R*(n-1)) = 100
    if (K < 1) K = 1;

    float* ws = (float*)d_ws;
    float* out = (float*)d_out;

    dtl_rows<<<(M + 3) / 4, 256, 0, stream>>>(in, tgt, ws, M, N, K);
    dtl_reduce<<<1, 256, 0, stream>>>(ws, out, M);
}

// Round 6
// 234.725 us; speedup vs baseline: 1.0557x; 1.0557x over previous
//
#include <hip/hip_runtime.h>
#include <stdint.h>

#define TW_LO 2.10f       // window around K-th order statistic (2.326 +/- 6 sigma)
#define TW_HI 2.55f
#define WSEG 96           // per-wave capture segment (E=31/wave, +11 sigma)
#define NBIN 256          // histogram bins over (TW_LO, TW_HI]
#define BIN_SCALE (256.0f / 0.45f)
#define BCAP 24           // members of one selected bin (E~0.5)
#define DELTA_W 0.2f
#define NITER 10          // 10*256*4 = 10240 >= 10001: whole row in one batch

static __device__ __forceinline__ unsigned f2u(float x) {
    unsigned b = __float_as_uint(x);
    return (b & 0x80000000u) ? ~b : (b | 0x80000000u);
}
static __device__ __forceinline__ float u2f(unsigned u) {
    unsigned b = (u & 0x80000000u) ? (u & 0x7fffffffu) : ~u;
    return __uint_as_float(b);
}
static __device__ __forceinline__ int lane_prefix(unsigned long long m) {
    return __builtin_amdgcn_mbcnt_hi((unsigned)(m >> 32),
                                     __builtin_amdgcn_mbcnt_lo((unsigned)m, 0));
}
static __device__ __forceinline__ void wave_lds_fence() {
    asm volatile("s_waitcnt lgkmcnt(0)" ::: "memory");
}

__global__ __launch_bounds__(256) void dtl_rows(const float* __restrict__ in,
                                                const int* __restrict__ targets,
                                                float* __restrict__ ws,
                                                int N, int K) {
    __shared__ float wlist[4 * WSEG];
    __shared__ int   hist[NBIN];
    __shared__ float hsum[NBIN];
    __shared__ int   wcnts[4];
    __shared__ int   schi[4];
    __shared__ float ssum[4];
    __shared__ float s_posv;
    __shared__ float arr1[BCAP], arr2[BCAP];
    __shared__ int   s_m1, s_m2;
    __shared__ int   s_b1, s_b2, s_CA1, s_CA2;
    __shared__ float s_CS1, s_CS2;

    const int row = blockIdx.x;
    const int tid = threadIdx.x;
    const int lane = tid & 63;
    const int wid = tid >> 6;

    const size_t rowoff = (size_t)row * (size_t)N;
    const float* __restrict__ p = in + rowoff;
    const int tgt = targets[row];

    // LDS is re-poisoned 0xAA every iteration: init everything we read.
    hist[tid] = 0;                 // NBIN == blockDim
    hsum[tid] = 0.f;
    if (tid == 0) {
        s_m1 = 0; s_m2 = 0; s_b1 = -1; s_b2 = -1;
        s_CA1 = 0; s_CA2 = 0; s_CS1 = 0.f; s_CS2 = 0.f;
        s_posv = p[tgt];
    }
    __syncthreads();

    int chi = 0;                   // per-thread #{x > TW_HI}
    float sum_hi = 0.f;            // per-thread sum (1+x)^2 over x > TW_HI
    int wc = 0;                    // WAVE-UNIFORM capture count (stays in SGPR)
    float* __restrict__ mylist = wlist + wid * WSEG;

    auto proc = [&](float x, bool valid) {
        bool hi = valid && (x > TW_HI);
        float t = 1.f + x;
        float z = hi ? t : 0.f;                  // branchless hi accumulate
        sum_hi = fmaf(z, z, sum_hi);
        chi += hi ? 1 : 0;
        bool win = valid && (x > TW_LO) && !hi;  // window (TW_LO, TW_HI]
        unsigned long long m = __ballot(win);
        if (win) {                               // no atomic, no DS round-trip
            int idx = wc + lane_prefix(m);
            if (idx < WSEG) mylist[idx] = x;     // plain ds_write
        }
        wc += (int)__popcll(m);                  // uniform SALU update
    };

    // ---- hot loop: one block streams one row ----
    int a0 = (int)((4 - (rowoff & 3)) & 3);      // odd row stride: align fix
    if (a0 > N) a0 = N;
    const int nv = (N - a0) >> 2;
    const int tail0 = a0 + nv * 4;

    {   // head (<=3 real lanes; all threads participate in ballots)
        bool v = tid < a0;
        float x = 0.f;
        if (v) x = p[tid];
        proc(x, v);
    }
    {   // tail (<=3 real lanes)
        int c = tail0 + tid;
        bool v = c < N;
        float x = 0.f;
        if (v) x = p[c];
        proc(x, v);
    }

    const float4* __restrict__ pv = (const float4*)(p + a0);
    for (int base = 0; base < nv; base += NITER * 256) {
        float4 buf[NITER];
#pragma unroll
        for (int it = 0; it < NITER; ++it) {     // all loads issued up front
            int i = base + it * 256 + tid;
            buf[it] = (i < nv) ? pv[i] : make_float4(0.f, 0.f, 0.f, 0.f);
        }
#pragma unroll
        for (int it = 0; it < NITER; ++it) {
            int i = base + it * 256 + tid;
            bool v = i < nv;
            proc(buf[it].x, v); proc(buf[it].y, v);
            proc(buf[it].z, v); proc(buf[it].w, v);
        }
    }

    // publish per-wave results
#pragma unroll
    for (int off = 32; off > 0; off >>= 1) {
        chi += __shfl_xor(chi, off);
        sum_hi += __shfl_xor(sum_hi, off);
    }
    if (lane == 0) { wcnts[wid] = wc; schi[wid] = chi; ssum[wid] = sum_hi; }
    __syncthreads();

    // ---- build histogram from lists (all 256 threads) ----
    for (int k = 0; k < 4; ++k) {
        int nk = min(wcnts[k], WSEG);
        for (int i = tid; i < nk; i += 256) {
            float x = wlist[k * WSEG + i];
            int bin = min((int)((x - TW_LO) * BIN_SCALE), NBIN - 1);
            atomicAdd(&hist[bin], 1);
            float t = 1.f + x;
            atomicAdd(&hsum[bin], t * t);
        }
    }
    __syncthreads();
    if (wid != 0) return;          // waves 1-3 done (no further barriers)

    // ---- wave0: selection ----
    const int chiT = schi[0] + schi[1] + schi[2] + schi[3];
    const float sumT = ssum[0] + ssum[1] + ssum[2] + ssum[3];
    const int n0 = wcnts[0], n1 = wcnts[1], n2 = wcnts[2], n3 = wcnts[3];
    const bool ovf = (n0 > WSEG) | (n1 > WSEG) | (n2 > WSEG) | (n3 > WSEG);
    const int nW = min(n0, WSEG) + min(n1, WSEG) + min(n2, WSEG) + min(n3, WSEG);
    const int j1 = K - chiT;       // rank of K-th largest of S within window
    const int j2 = K + 1 - chiT;   // rank of (K+1)-th
    const float posv = s_posv;

    bool fb = ovf || (j1 < 1) || (j2 > nW);
    if (!fb) {
        // reverse scan: lane L owns bins 4L..4L+3
        int h0 = hist[lane * 4], h1 = hist[lane * 4 + 1];
        int h2 = hist[lane * 4 + 2], h3 = hist[lane * 4 + 3];
        float q0 = hsum[lane * 4], q1 = hsum[lane * 4 + 1];
        float q2 = hsum[lane * 4 + 2], q3 = hsum[lane * 4 + 3];
        int cum = h0 + h1 + h2 + h3;
        float csum = q0 + q1 + q2 + q3;
#pragma unroll
        for (int off = 1; off < 64; off <<= 1) {   // reverse inclusive scan
            int cv = __shfl_down(cum, off);
            float sv = __shfl_down(csum, off);
            if (lane + off < 64) { cum += cv; csum += sv; }
        }
        int caN = __shfl_down(cum, 1);             // strictly-above-lane counts
        float csN = __shfl_down(csum, 1);
        if (lane == 63) { caN = 0; csN = 0.f; }
        {   // walk this lane's 4 bins top-down
            int hh[4] = {h3, h2, h1, h0};
            float qq[4] = {q3, q2, q1, q0};
            int ca = caN; float cs = csN;
#pragma unroll
            for (int t = 0; t < 4; ++t) {
                int b = lane * 4 + 3 - t;
                if (ca < j1 && j1 <= ca + hh[t]) { s_b1 = b; s_CA1 = ca; s_CS1 = cs; }
                if (ca < j2 && j2 <= ca + hh[t]) { s_b2 = b; s_CA2 = ca; s_CS2 = cs; }
                ca += hh[t]; cs += qq[t];
            }
        }
        wave_lds_fence();
        const int b1 = s_b1, b2 = s_b2;
        if (b1 < 0 || b2 < 0) fb = true;

        if (!fb) {
            // collect members of b1 (and b2 if distinct)
            for (int k = 0; k < 4; ++k) {
                int nk = min(wcnts[k], WSEG);
                for (int i = lane; i < nk; i += 64) {
                    float x = wlist[k * WSEG + i];
                    int bin = min((int)((x - TW_LO) * BIN_SCALE), NBIN - 1);
                    if (bin == b1) {
                        int a = atomicAdd(&s_m1, 1);
                        if (a < BCAP) arr1[a] = x;
                    } else if (bin == b2) {
                        int a = atomicAdd(&s_m2, 1);
                        if (a < BCAP) arr2[a] = x;
                    }
                }
            }
            wave_lds_fence();
            const int m1 = s_m1, m2 = s_m2;
            if (m1 > BCAP || m2 > BCAP) fb = true;

            if (!fb) {
                // wave-parallel rank-select inside a tiny bin
                auto rank_sel = [&](const float* arr, int m, int r,
                                    float& t_out, int& mgt, float& ssel, int& cteq) {
                    float v = (lane < m) ? arr[lane] : -1e30f;
                    int g = 0, ge = 0;
                    for (int j = 0; j < m; ++j) {
                        float u = arr[j];
                        g += (u > v); ge += (u >= v);
                    }
                    bool isT = (lane < m) && (g < r) && (r <= ge);
                    unsigned long long mm = __ballot(isT);
                    int fl = __ffsll(mm) - 1;     // guaranteed nonempty
                    float t = __shfl(v, fl);
                    mgt = __shfl(g, fl);
                    float contrib = (lane < m && v > t) ? (1.f + v) * (1.f + v) : 0.f;
                    int eq = (lane < m && v == t) ? 1 : 0;
#pragma unroll
                    for (int off = 32; off > 0; off >>= 1) {
                        contrib += __shfl_xor(contrib, off);
                        eq += __shfl_xor(eq, off);
                    }
                    t_out = t; ssel = contrib; cteq = eq;
                };

                float t1, ssel1; int mgt1, cteq1;
                rank_sel(arr1, m1, j1 - s_CA1, t1, mgt1, ssel1, cteq1);
                const int g1 = chiT + s_CA1 + mgt1;
                const float e1 = 1.f + t1;
                const float S1 = sumT + s_CS1 + ssel1 + (float)(K - g1) * e1 * e1;

                float ans = 0.f; bool ok = true;
                if (posv < t1) {
                    ans = S1;                     // top-K unchanged by exclusion
                } else if (posv > t1) {           // target in top-K: use top-(K+1)
                    const float* a2 = (b2 == b1) ? arr1 : arr2;
                    const int mm2 = (b2 == b1) ? m1 : m2;
                    const int CA2 = (b2 == b1) ? s_CA1 : s_CA2;
                    const float CS2 = (b2 == b1) ? s_CS1 : s_CS2;
                    float t2, ssel2; int mgt2, cteq2;
                    rank_sel(a2, mm2, j2 - CA2, t2, mgt2, ssel2, cteq2);
                    const int g2 = chiT + CA2 + mgt2;
                    const float e2 = 1.f + t2;
                    const float S2 = sumT + CS2 + ssel2 + (float)(K + 1 - g2) * e2 * e2;
                    const float pe = 1.f + posv;
                    ans = S2 - pe * pe;
                } else {                          // posv == t1: tie bookkeeping
                    if (g1 + cteq1 >= K + 1) ans = S1;
                    else ok = false;
                }
                if (ok) {
                    if (lane == 0) {
                        float d = 1.f - posv;
                        ws[row] = d * d + DELTA_W * ans / (float)K;
                    }
                    return;
                }
                fb = true;
            }
        }
    }

    // ---- exact global fallback (never hit for N(0,1) data) ----
    {
        unsigned thr = 0;
        for (int bit = 31; bit >= 0; --bit) {
            unsigned trial = thr | (1u << bit);
            int cnt = 0;
            for (int i = lane; i < N; i += 64) {
                if (i == tgt) continue;
                cnt += (f2u(p[i]) >= trial);
            }
            for (int off = 32; off > 0; off >>= 1) cnt += __shfl_down(cnt, off);
            cnt = __shfl(cnt, 0);
            if (cnt >= K) thr = trial;
        }
        int gt = 0; float s = 0.f;
        for (int i = lane; i < N; i += 64) {
            if (i == tgt) continue;
            unsigned u = f2u(p[i]);
            if (u > thr) { gt++; float e = 1.f + u2f(u); s += e * e; }
        }
        for (int off = 32; off > 0; off >>= 1) {
            gt += __shfl_down(gt, off); s += __shfl_down(s, off);
        }
        if (lane == 0) {
            float et = 1.f + u2f(thr);
            float sum = s + (float)(K - gt) * et * et;
            float d = 1.f - s_posv;
            ws[row] = d * d + DELTA_W * sum / (float)K;
        }
    }
}

__global__ __launch_bounds__(256) void dtl_reduce(const float* __restrict__ ws,
                                                  float* __restrict__ out, int M) {
    __shared__ float sh[4];
    float s = 0.f;
    for (int i = threadIdx.x; i < M; i += 256) s += ws[i];
    for (int off = 32; off > 0; off >>= 1) s += __shfl_down(s, off);
    int wid = threadIdx.x >> 6;
    if ((threadIdx.x & 63) == 0) sh[wid] = s;
    __syncthreads();
    if (threadIdx.x == 0) out[0] = (sh[0] + sh[1] + sh[2] + sh[3]) / (float)M;
}

extern "C" void kernel_launch(void* const* d_in, const int* in_sizes, int n_in,
                              void* d_out, int out_size, void* d_ws, size_t ws_size,
                              hipStream_t stream) {
    const float* in = (const float*)d_in[0];
    const int* tgt = (const int*)d_in[1];
    const int M = in_sizes[1];
    const int N = in_sizes[0] / M;
    int K = (int)(0.01 * (double)(N - 1));  // matches Python int(R*(n-1)) = 100
    if (K < 1) K = 1;

    float* ws = (float*)d_ws;
    float* out = (float*)d_out;

    dtl_rows<<<M, 256, 0, stream>>>(in, tgt, ws, N, K);
    dtl_reduce<<<1, 256, 0, stream>>>(ws, out, M);
}